// Round 6
// baseline (82.649 us; speedup 1.0000x reference)
//
#include <hip/hip_runtime.h>
#include <hip/hip_fp16.h>
#include <math.h>

#define RES 256
#define TPAD 364          // padded texture dim: image rows -53..310 per axis
#define N_ANGLES 256
#define BATCH 8

#define SCH 16            // s-chunk per block
#define TCH 64            // t-chunk per block
#define NTC 4             // 256 / TCH
#define ROWS 78           // band rows
#define BW 28             // band width (texels)
#define NTEX (ROWS * BW)  // 2184 texels, 34.9 KB

typedef _Float16 h2 __attribute__((ext_vector_type(2)));

__device__ inline h2 u2h(unsigned int u) { return __builtin_bit_cast(h2, u); }
__device__ inline unsigned int h2u(h2 h) { return __builtin_bit_cast(unsigned int, h); }

// Batch-packed padded texture: T[r][c] = 8 x fp16 = {img_b(r-53, c-53)}_{b=0..7}
// (16B/texel), zero outside the image. Q = normal, QT = transposed.
__global__ void prep_pack(const float* __restrict__ imgs,
                          unsigned int* __restrict__ Qw,
                          unsigned int* __restrict__ QTw) {
    int idx = blockIdx.x * blockDim.x + threadIdx.x;
    const int total = 2 * TPAD * TPAD * 4;   // orient x pixel x batch-pair
    if (idx >= total) return;
    int pair   = idx & 3;
    int px     = (idx >> 2) % (TPAD * TPAD);
    int orient = (idx >> 2) / (TPAD * TPAD);
    int c = px % TPAD, r = px / TPAD;
    int rr = orient ? c : r;
    int cc = orient ? r : c;
    unsigned ri = (unsigned)(rr - 53), ci = (unsigned)(cc - 53);
    float v0 = 0.0f, v1 = 0.0f;
    if (ri < RES && ci < RES) {
        const float* p = imgs + ((size_t)(pair * 2) * RES + ri) * RES + ci;
        v0 = p[0];
        v1 = p[RES * RES];
    }
    __half2 h = __halves2half2(__float2half_rn(v0), __float2half_rn(v1));
    (orient ? QTw : Qw)[px * 4 + pair] = *reinterpret_cast<unsigned int*>(&h);
}

// Block = (angle, s-chunk 16, t-chunk 64). Stage the sheared texel band the
// block's samples touch into LDS (per-row column offset cb(r), slope m=Ct/Rt),
// then each thread samples 4 t-steps with 4 ds_read_b128 bilinear taps.
__global__ __launch_bounds__(256, 4) void radon_kernel(
        const uint4* __restrict__ Q,
        const uint4* __restrict__ QT,
        const float* __restrict__ angles,
        float* __restrict__ part) {
    __shared__ uint4 band[NTEX];
    __shared__ float scr[4][SCH][BATCH];

    const int tid = threadIdx.x;
    const int a  = blockIdx.x;
    const int s0 = blockIdx.y * SCH;
    const int tc = blockIdx.z;
    const int t0 = tc * TCH;

    float theta = angles[a];
    float sn, cs;
    sincosf(theta, &sn, &cs);

    // Orientation: |Rt| = max(|cos|,|sin|) >= 0.7071
    float Rs, Rt, Cs, Ct;
    const uint4* img;
    if (fabsf(cs) >= fabsf(sn)) { Rs = sn; Rt = cs;  Cs = cs; Ct = -sn; img = Q; }
    else                        { Rs = cs; Rt = -sn; Cs = sn; Ct = cs;  img = QT; }

    const float m   = Ct / Rt;                         // |m| <= 1
    const float smc = (float)s0 - 120.0f;              // s0+7.5-127.5
    const float tmc = (float)t0 - 96.0f;               // t0+31.5-127.5
    const float prc = fmaf(smc, Rs, fmaf(tmc, Rt, 180.5f));  // block-center ppr
    const float pcc = fmaf(smc, Cs, fmaf(tmc, Ct, 180.5f));  // block-center ppc
    const int   r0  = (int)floorf(prc - (7.5f * fabsf(Rs) + 31.5f * fabsf(Rt))) - 1;
    const float r0f = (float)r0;

    // ---- stage the sheared band (coalesced rows of BW texels) ----
    for (int j = 0; j < 9; ++j) {
        int idx = tid + j * 256;
        if (idx < NTEX) {
            int rs = idx / BW;
            int u  = idx - rs * BW;
            int r  = r0 + rs;
            float cbf = floorf(fmaf((float)r - prc, m, pcc));
            int c = (int)cbf - 13 + u;
            uint4 v = make_uint4(0u, 0u, 0u, 0u);
            if ((unsigned)r < TPAD && (unsigned)c < TPAD)
                v = img[r * TPAD + c];
            unsigned addr = (unsigned)((rs * BW + u) << 4) ^ (unsigned)((rs & 7) << 4);
            *(uint4*)((char*)band + addr) = v;
        }
    }
    __syncthreads();

    // ---- sample: lane = s(4b) x tq(4b); each thread 4 t-steps of stride 16 ----
    const int sl = tid & 15;
    const int tq = tid >> 4;
    const float s_c = (float)(s0 + sl) - 127.5f;
    const float prA = fmaf(s_c, Rs, 180.5f);
    const float pcA = fmaf(s_c, Cs, 180.5f);
    float t_c = (float)(t0 + tq) - 127.5f;

    h2 acc0 = {}, acc1 = {}, acc2 = {}, acc3 = {};

    #pragma unroll
    for (int i = 0; i < 4; ++i) {
        float ppr = fmaf(t_c, Rt, prA);
        float ppc = fmaf(t_c, Ct, pcA);
        t_c += 16.0f;
        float fr = floorf(ppr), fc = floorf(ppc);
        float wy = ppr - fr,  wx = ppc - fc;
        // per-row column bases (bitwise-identical expression to staging)
        float cb0 = floorf(fmaf(fr - prc, m, pcc));
        float cb1 = floorf(fmaf((fr + 1.0f) - prc, m, pcc));
        int rs = (int)(fr - r0f);
        int u0 = (int)(fc - cb0 + 13.0f);
        int u1 = (int)(fc - cb1 + 13.0f);
        unsigned pre0 = (unsigned)((rs * BW + u0) << 4);
        unsigned swz0 = (unsigned)((rs & 7) << 4);
        unsigned pre1 = (unsigned)(((rs + 1) * BW + u1) << 4);
        unsigned swz1 = (unsigned)(((rs + 1) & 7) << 4);
        uint4 q00 = *(const uint4*)((const char*)band + (pre0 ^ swz0));
        uint4 q01 = *(const uint4*)((const char*)band + ((pre0 + 16) ^ swz0));
        uint4 q10 = *(const uint4*)((const char*)band + (pre1 ^ swz1));
        uint4 q11 = *(const uint4*)((const char*)band + ((pre1 + 16) ^ swz1));

        float wy1  = 1.0f - wy;
        float w01f = wx * wy1;        // (row, col+1)
        float w00f = wy1 - w01f;      // (row, col)
        float w11f = wx * wy;         // (row+1, col+1)
        float w10f = wy - w11f;       // (row+1, col)
        auto pk = [](float x) {
            auto v = __builtin_amdgcn_cvt_pkrtz(x, x);
            return __builtin_bit_cast(h2, v);
        };
        h2 w00 = pk(w00f), w01 = pk(w01f), w10 = pk(w10f), w11 = pk(w11f);

        acc0 = w00 * u2h(q00.x) + acc0;
        acc1 = w00 * u2h(q00.y) + acc1;
        acc2 = w00 * u2h(q00.z) + acc2;
        acc3 = w00 * u2h(q00.w) + acc3;
        acc0 = w01 * u2h(q01.x) + acc0;
        acc1 = w01 * u2h(q01.y) + acc1;
        acc2 = w01 * u2h(q01.z) + acc2;
        acc3 = w01 * u2h(q01.w) + acc3;
        acc0 = w10 * u2h(q10.x) + acc0;
        acc1 = w10 * u2h(q10.y) + acc1;
        acc2 = w10 * u2h(q10.z) + acc2;
        acc3 = w10 * u2h(q10.w) + acc3;
        acc0 = w11 * u2h(q11.x) + acc0;
        acc1 = w11 * u2h(q11.y) + acc1;
        acc2 = w11 * u2h(q11.z) + acc2;
        acc3 = w11 * u2h(q11.w) + acc3;
    }

    // ---- reduce tq: in-wave (lane bits 4,5), then cross-wave via LDS ----
    unsigned vv;
    #define R1632(A) \
        vv = __shfl_xor(h2u(A), 16); A = A + u2h(vv); \
        vv = __shfl_xor(h2u(A), 32); A = A + u2h(vv);
    R1632(acc0) R1632(acc1) R1632(acc2) R1632(acc3)
    #undef R1632

    const int w = tid >> 6;
    if ((tid & 63) < 16) {
        scr[w][sl][0] = (float)acc0.x;  scr[w][sl][1] = (float)acc0.y;
        scr[w][sl][2] = (float)acc1.x;  scr[w][sl][3] = (float)acc1.y;
        scr[w][sl][4] = (float)acc2.x;  scr[w][sl][5] = (float)acc2.y;
        scr[w][sl][6] = (float)acc3.x;  scr[w][sl][7] = (float)acc3.y;
    }
    __syncthreads();

    if (tid < SCH * BATCH) {          // 128 threads
        int ss = tid & 15, b = tid >> 4;
        float sum = scr[0][ss][b] + scr[1][ss][b] + scr[2][ss][b] + scr[3][ss][b];
        part[((size_t)(tc * BATCH + b) * N_ANGLES + a) * RES + (s0 + ss)] = sum;
    }
}

__global__ void combine(const float4* __restrict__ p, float4* __restrict__ out) {
    const int n4 = BATCH * N_ANGLES * RES / 4;   // 131072
    int i = blockIdx.x * blockDim.x + threadIdx.x;
    if (i < n4) {
        float4 A = p[i], B = p[i + n4], C = p[i + 2 * n4], D = p[i + 3 * n4];
        out[i] = make_float4(A.x + B.x + C.x + D.x,
                             A.y + B.y + C.y + D.y,
                             A.z + B.z + C.z + D.z,
                             A.w + B.w + C.w + D.w);
    }
}

extern "C" void kernel_launch(void* const* d_in, const int* in_sizes, int n_in,
                              void* d_out, int out_size, void* d_ws, size_t ws_size,
                              hipStream_t stream) {
    const float* imgs   = (const float*)d_in[0];
    const float* angles = (const float*)d_in[1];
    float* out = (float*)d_out;

    const size_t texN = (size_t)TPAD * TPAD;            // texels per orientation
    uint4* Q    = (uint4*)d_ws;                         // 2.12 MB
    uint4* QT   = Q + texN;                             // 2.12 MB
    float* part = (float*)(QT + texN);                  // 4 x 2 MB partials

    const int prep_total = 2 * TPAD * TPAD * 4;
    prep_pack<<<(prep_total + 255) / 256, 256, 0, stream>>>(
        imgs, (unsigned int*)Q, (unsigned int*)QT);

    dim3 grid(N_ANGLES, RES / SCH, NTC);                // 256 x 16 x 4 blocks
    radon_kernel<<<grid, 256, 0, stream>>>(Q, QT, angles, part);

    const int n4 = BATCH * N_ANGLES * RES / 4;
    combine<<<(n4 + 255) / 256, 256, 0, stream>>>((const float4*)part, (float4*)out);
}

// Round 7
// 55.467 us; speedup vs baseline: 1.4901x; 1.4901x over previous
//
#include <hip/hip_runtime.h>
#include <hip/hip_fp16.h>
#include <math.h>

#define RES 256
#define TPAD 364          // padded texture dim: image rows -53..310 per axis
#define N_ANGLES 256
#define BATCH 8
#define ROWB (TPAD * 16)  // texture row pitch in bytes (5824)

typedef _Float16 h2 __attribute__((ext_vector_type(2)));
__device__ inline h2 u2h(unsigned int u) { return __builtin_bit_cast(h2, u); }
__device__ inline unsigned int h2u(h2 h) { return __builtin_bit_cast(unsigned int, h); }

// Batch-packed padded texture: T[r][c] = 8 x fp16 = {img_b(r-53, c-53)}_{b=0..7}
// (16B/texel), zero outside image => no bounds checks at sample time.
__global__ void prep_pack(const float* __restrict__ imgs,
                          unsigned int* __restrict__ Qw,
                          unsigned int* __restrict__ QTw) {
    int idx = blockIdx.x * blockDim.x + threadIdx.x;
    const int total = 2 * TPAD * TPAD * 4;   // orient x pixel x batch-pair
    if (idx >= total) return;
    int pair   = idx & 3;
    int px     = (idx >> 2) % (TPAD * TPAD);
    int orient = (idx >> 2) / (TPAD * TPAD);
    int c = px % TPAD, r = px / TPAD;
    int rr = orient ? c : r;
    int cc = orient ? r : c;
    unsigned ri = (unsigned)(rr - 53), ci = (unsigned)(cc - 53);
    float v0 = 0.0f, v1 = 0.0f;
    if (ri < RES && ci < RES) {
        const float* p = imgs + ((size_t)(pair * 2) * RES + ri) * RES + ci;
        v0 = p[0];
        v1 = p[RES * RES];
    }
    __half2 h = __halves2half2(__float2half_rn(v0), __float2half_rn(v1));
    (orient ? QTw : Qw)[px * 4 + pair] = *reinterpret_cast<unsigned int*>(&h);
}

// Lane layout: tap(2b) | t-parity(1b) | s(3b). grid = (angle, s/32, t-half).
// Inner loop: 4-deep software pipeline {4x addr+weight -> 4x load -> 4x pk_fma}.
__global__ __launch_bounds__(256) void radon_kernel(
        const uint4* __restrict__ Q,
        const uint4* __restrict__ QT,
        const float* __restrict__ angles,
        float* __restrict__ part) {
    const int tap  = threadIdx.x & 3;
    const int tpar = (threadIdx.x >> 2) & 1;
    const int s    = blockIdx.y * 32 + (threadIdx.x >> 3);
    const int a    = blockIdx.x;
    const int z    = blockIdx.z;

    float theta = angles[a];
    float sn, cs;
    sincosf(theta, &sn, &cs);

    float Rs, Rt, Cs, Ct;
    const uint4* img;
    if (fabsf(cs) >= fabsf(sn)) { Rs = sn; Rt = cs;  Cs = cs; Ct = -sn; img = Q; }
    else                        { Rs = cs; Rt = -sn; Cs = sn; Ct = cs;  img = QT; }
    const char* bimg = (const char*)img;               // wave-uniform base

    const float s_c = (float)s - 127.5f;
    const float pr0 = fmaf(s_c, Rs, 180.5f) - 127.5f * Rt;
    const float pc0 = fmaf(s_c, Cs, 180.5f) - 127.5f * Ct;

    // Work-skip clip: nonzero bilinear only for padded coords in [52, 309].
    const float LO = 52.0f, HI = 309.0f;
    float tmin = 0.0f, tmax = 255.0f;
    {
        float inv = 1.0f / Rt;
        float ta = (LO - pr0) * inv, tb = (HI - pr0) * inv;
        tmin = fmaxf(tmin, fminf(ta, tb));
        tmax = fminf(tmax, fmaxf(ta, tb));
    }
    if (fabsf(Ct) > 1e-6f) {
        float inv = 1.0f / Ct;
        float ta = (LO - pc0) * inv, tb = (HI - pc0) * inv;
        tmin = fmaxf(tmin, fminf(ta, tb));
        tmax = fminf(tmax, fmaxf(ta, tb));
    } else if (!(pc0 >= LO && pc0 <= HI)) {
        tmax = -1.0f;
    }

    // This lane covers t = z*128 + tpar + 2*i, i in [0,64). Chunk i by 16.
    const float tb0 = (float)(z * 128 + tpar);
    int i0 = (int)ceilf((tmin - tb0) * 0.5f);
    int i1 = (int)floorf((tmax - tb0) * 0.5f);
    i0 = max(i0, 0);
    i1 = min(i1, 63);
    int c0 = i0 >> 4, c1 = i1 >> 4;
    if (i1 < i0) { c0 = 1; c1 = 0; }

    // Per-tap constants.
    const int dr = tap >> 1, dc = tap & 1;
    const unsigned tapoff = (unsigned)(dr * ROWB + dc * 16);
    const float xb = dc ? 0.0f : 1.0f, xs = dc ? 1.0f : -1.0f;
    const float yb = dr ? 0.0f : 1.0f, ys = dr ? 1.0f : -1.0f;

    float a0 = 0.f, a1 = 0.f, a2 = 0.f, a3 = 0.f;
    float a4 = 0.f, a5 = 0.f, a6 = 0.f, a7 = 0.f;

    for (int c = c0; c <= c1; ++c) {
        h2 h0 = {}, h1 = {}, h2v = {}, h3 = {};
        float tf = fmaf(32.0f, (float)c, tb0);
        #pragma unroll
        for (int g = 0; g < 4; ++g) {
            unsigned boff[4];
            h2 wv[4];
            #pragma unroll
            for (int k = 0; k < 4; ++k) {
                float ppr = fmaf(tf, Rt, pr0);
                float ppc = fmaf(tf, Ct, pc0);
                tf += 2.0f;
                float wy, wx;
                int ir, ic;
                asm("v_fract_f32 %0, %1"        : "=v"(wy) : "v"(ppr));
                asm("v_fract_f32 %0, %1"        : "=v"(wx) : "v"(ppc));
                asm("v_cvt_flr_i32_f32 %0, %1"  : "=v"(ir) : "v"(ppr));
                asm("v_cvt_flr_i32_f32 %0, %1"  : "=v"(ic) : "v"(ppc));
                unsigned x = ((unsigned)ic << 4) + tapoff;     // v_lshl_add_u32
                unsigned bo;
                asm("v_mad_u32_u24 %0, %1, %2, %3"
                    : "=v"(bo) : "v"(ir), "s"(ROWB), "v"(x));
                boff[k] = bo;
                float w = fmaf(xs, wx, xb) * fmaf(ys, wy, yb);
                auto pkr = __builtin_amdgcn_cvt_pkrtz(w, w);
                wv[k] = __builtin_bit_cast(h2, pkr);
            }
            uint4 q[4];
            #pragma unroll
            for (int k = 0; k < 4; ++k)
                q[k] = *(const uint4*)(bimg + boff[k]);
            #pragma unroll
            for (int k = 0; k < 4; ++k) {
                h0  = wv[k] * u2h(q[k].x) + h0;
                h1  = wv[k] * u2h(q[k].y) + h1;
                h2v = wv[k] * u2h(q[k].z) + h2v;
                h3  = wv[k] * u2h(q[k].w) + h3;
            }
        }
        float2 f;
        f.x = (float)h0.x;  f.y = (float)h0.y;  a0 += f.x; a1 += f.y;
        f.x = (float)h1.x;  f.y = (float)h1.y;  a2 += f.x; a3 += f.y;
        f.x = (float)h2v.x; f.y = (float)h2v.y; a4 += f.x; a5 += f.y;
        f.x = (float)h3.x;  f.y = (float)h3.y;  a6 += f.x; a7 += f.y;
    }

    // Combine tap lanes (bits 0-1) and t-parity (bit 2).
    #define RED(x) { x += __shfl_xor(x, 1); x += __shfl_xor(x, 2); x += __shfl_xor(x, 4); }
    RED(a0) RED(a1) RED(a2) RED(a3)
    RED(a4) RED(a5) RED(a6) RED(a7)
    #undef RED

    if ((threadIdx.x & 7) == 0) {
        const size_t AR = (size_t)N_ANGLES * RES;
        size_t base = ((size_t)z * BATCH) * AR + (size_t)a * RES + s;
        part[base         ] = a0;
        part[base + 1 * AR] = a1;
        part[base + 2 * AR] = a2;
        part[base + 3 * AR] = a3;
        part[base + 4 * AR] = a4;
        part[base + 5 * AR] = a5;
        part[base + 6 * AR] = a6;
        part[base + 7 * AR] = a7;
    }
}

__global__ void combine(const float4* __restrict__ p, float4* __restrict__ out) {
    const int n4 = BATCH * N_ANGLES * RES / 4;
    int i = blockIdx.x * blockDim.x + threadIdx.x;
    if (i < n4) {
        float4 x = p[i];
        float4 y = p[i + n4];
        out[i] = make_float4(x.x + y.x, x.y + y.y, x.z + y.z, x.w + y.w);
    }
}

extern "C" void kernel_launch(void* const* d_in, const int* in_sizes, int n_in,
                              void* d_out, int out_size, void* d_ws, size_t ws_size,
                              hipStream_t stream) {
    const float* imgs   = (const float*)d_in[0];
    const float* angles = (const float*)d_in[1];
    float* out = (float*)d_out;

    const size_t texN = (size_t)TPAD * TPAD;
    uint4* Q    = (uint4*)d_ws;                         // 2.12 MB
    uint4* QT   = Q + texN;                             // 2.12 MB
    float* part = (float*)(QT + texN);                  // 2 x 2 MB partials

    const int prep_total = 2 * TPAD * TPAD * 4;
    prep_pack<<<(prep_total + 255) / 256, 256, 0, stream>>>(
        imgs, (unsigned int*)Q, (unsigned int*)QT);

    dim3 grid(N_ANGLES, 8, 2);                          // 4096 blocks x 256 thr
    radon_kernel<<<grid, 256, 0, stream>>>(Q, QT, angles, part);

    const int n4 = BATCH * N_ANGLES * RES / 4;
    combine<<<(n4 + 255) / 256, 256, 0, stream>>>((const float4*)part, (float4*)out);
}